// Round 5
// baseline (394.434 us; speedup 1.0000x reference)
//
#include <hip/hip_runtime.h>

#define HID 128
#define NIN 21
#define EIN 2
#define NCLS 4

// LDS row layout (per hidden-dim d), stride 124 floats (496B = 31*16B, 16B-aligned):
//  [0..62]   node-gate weights interleaved as triples: (wi_k, wg_k, wo_k), k=0..20
//            wi,wo pre-scaled by L=log2(e); wg pre-scaled by 2L
//  [63..65]  combined node biases (same scaling): bi, bg, bo
//  [66..71]  edge weights (scaled): ewi0,ewi1, ewg0,ewg1, ewo0,ewo1
//  [72..74]  combined edge biases (scaled): ebi, ebg, ebo
//  [75..95]  L * W_nmpn[k][d]      (he coefficients), k=0..20
//  [96..116] L * W_nmpn[k][128+d]  (hn coefficients), k=0..20
//  [117..120] W_fc[c][d], c=0..3   (unscaled)
#define WSTRIDE 124

#define L2E   1.4426950408889634f   // log2(e)
#define L2E2  2.8853900817779268f   // 2*log2(e)

__device__ __forceinline__ float rcp_(float x) {
    return __builtin_amdgcn_rcpf(x);
}
__device__ __forceinline__ float exp2_(float x) {
    return __builtin_amdgcn_exp2f(x);
}
// input pre-scaled by L2E:  sigmoid(g) = 1/(1+2^(-g'))
__device__ __forceinline__ float sigmoid_pre(float gp) {
    return rcp_(1.0f + exp2_(-gp));
}
// input pre-scaled by 2*L2E: tanh(g) = 2/(1+2^(-g'')) - 1
__device__ __forceinline__ float tanh_pre(float gp) {
    return fmaf(2.0f, rcp_(1.0f + exp2_(-gp)), -1.0f);
}
// unscaled input
__device__ __forceinline__ float tanh_(float x) {
    return fmaf(2.0f, rcp_(1.0f + exp2_(-L2E2 * x)), -1.0f);
}

// 512 threads/block; lane pairs (2i,2i+1) share one node, split d-range 2-way.
// launch_bounds(512,2): VGPR budget 256 — compiler lands ~128, no spills
// (empirically (256,2)->128 no-spill; (512,4)->64+spill).
__global__ __launch_bounds__(512, 2)
void fused_gnn_kernel(const float* __restrict__ node_feat,  // N*21
                      const float* __restrict__ edge_feat,  // N*2
                      const float* __restrict__ W_ih_n,     // 512*21
                      const float* __restrict__ b_ih_n,     // 512
                      const float* __restrict__ b_hh_n,     // 512
                      const float* __restrict__ W_ih_e,     // 512*2
                      const float* __restrict__ b_ih_e,     // 512
                      const float* __restrict__ b_hh_e,     // 512
                      const float* __restrict__ W_nmpn,     // 21*256
                      const float* __restrict__ b_nmpn,     // 21
                      const float* __restrict__ W_fc,       // 4*128
                      const float* __restrict__ b_fc,       // 4
                      float* __restrict__ out,              // N*4
                      int N)
{
    __shared__ float lds[HID * WSTRIDE];   // 63488 B -> 2 blocks/CU -> 16 waves/CU

    const int tid = threadIdx.x;

    // ---------------- stage weights into LDS (once per block) ----------------
    if (tid < HID) {
        const int d = tid;
        float* row = &lds[d * WSTRIDE];
#pragma unroll
        for (int k = 0; k < NIN; ++k) {
            row[3 * k + 0] = L2E  * W_ih_n[(0 * HID + d) * NIN + k];
            row[3 * k + 1] = L2E2 * W_ih_n[(2 * HID + d) * NIN + k];
            row[3 * k + 2] = L2E  * W_ih_n[(3 * HID + d) * NIN + k];
        }
        row[63] = L2E  * (b_ih_n[0 * HID + d] + b_hh_n[0 * HID + d]);
        row[64] = L2E2 * (b_ih_n[2 * HID + d] + b_hh_n[2 * HID + d]);
        row[65] = L2E  * (b_ih_n[3 * HID + d] + b_hh_n[3 * HID + d]);
    } else if (tid < 2 * HID) {
        const int d = tid - HID;
        float* row = &lds[d * WSTRIDE];
        row[66] = L2E  * W_ih_e[(0 * HID + d) * EIN + 0];
        row[67] = L2E  * W_ih_e[(0 * HID + d) * EIN + 1];
        row[68] = L2E2 * W_ih_e[(2 * HID + d) * EIN + 0];
        row[69] = L2E2 * W_ih_e[(2 * HID + d) * EIN + 1];
        row[70] = L2E  * W_ih_e[(3 * HID + d) * EIN + 0];
        row[71] = L2E  * W_ih_e[(3 * HID + d) * EIN + 1];
        row[72] = L2E  * (b_ih_e[0 * HID + d] + b_hh_e[0 * HID + d]);
        row[73] = L2E2 * (b_ih_e[2 * HID + d] + b_hh_e[2 * HID + d]);
        row[74] = L2E  * (b_ih_e[3 * HID + d] + b_hh_e[3 * HID + d]);
#pragma unroll
        for (int k = 0; k < NIN; ++k) {
            row[75 + k] = L2E * W_nmpn[k * 2 * HID + d];
            row[96 + k] = L2E * W_nmpn[k * 2 * HID + HID + d];
        }
#pragma unroll
        for (int c = 0; c < NCLS; ++c) {
            row[117 + c] = W_fc[c * HID + d];
        }
    }
    __syncthreads();

    // ---------------- node assignment: 2 threads per node ----------------
    const int half = tid & 1;                         // d-range half
    const int node = blockIdx.x * 256 + (tid >> 1);   // 256 nodes per block
    const int nidx = (node < N) ? node : (N - 1);
    const int dbase = half * 64;

    float xn[NIN];
#pragma unroll
    for (int k = 0; k < NIN; ++k) xn[k] = node_feat[nidx * NIN + k];
    const float xe0 = edge_feat[nidx * EIN + 0];
    const float xe1 = edge_feat[nidx * EIN + 1];

    float acc[NIN];   // partial: L2E * (xn1 pre-activation), this half's d-sum
#pragma unroll
    for (int k = 0; k < NIN; ++k) acc[k] = half ? 0.0f : (L2E * b_nmpn[k]);
    float lg[NCLS];
#pragma unroll
    for (int k = 0; k < NCLS; ++k) lg[k] = half ? 0.0f : b_fc[k];

    // ================= iteration 1 (64 d's per thread) =================
#pragma unroll 2
    for (int dd = 0; dd < 64; ++dd) {
        const float* row = &lds[(dbase + dd) * WSTRIDE];

        float gi = row[63], gg = row[64], go = row[65];
#pragma unroll
        for (int k = 0; k < NIN; ++k) {
            gi = fmaf(xn[k], row[3 * k + 0], gi);
            gg = fmaf(xn[k], row[3 * k + 1], gg);
            go = fmaf(xn[k], row[3 * k + 2], go);
        }
        const float cn = sigmoid_pre(gi) * tanh_pre(gg);
        const float hn = sigmoid_pre(go) * tanh_(cn);

        const float ei = fmaf(xe0, row[66], fmaf(xe1, row[67], row[72]));
        const float eg = fmaf(xe0, row[68], fmaf(xe1, row[69], row[73]));
        const float eo = fmaf(xe0, row[70], fmaf(xe1, row[71], row[74]));
        const float ce = sigmoid_pre(ei) * tanh_pre(eg);
        const float he = sigmoid_pre(eo) * tanh_(ce);

#pragma unroll
        for (int k = 0; k < NIN; ++k) {
            acc[k] = fmaf(he, row[75 + k], fmaf(hn, row[96 + k], acc[k]));
        }
    }

    // ---- combine halves (lane pair 2i <-> 2i+1), both lanes get full sum ----
#pragma unroll
    for (int k = 0; k < NIN; ++k) {
        acc[k] += __shfl_xor(acc[k], 1);
        xn[k] = sigmoid_pre(acc[k]);
    }

    // ================= iteration 2 (only h_n matters) =================
#pragma unroll 2
    for (int dd = 0; dd < 64; ++dd) {
        const float* row = &lds[(dbase + dd) * WSTRIDE];

        float gi = row[63], gg = row[64], go = row[65];
#pragma unroll
        for (int k = 0; k < NIN; ++k) {
            gi = fmaf(xn[k], row[3 * k + 0], gi);
            gg = fmaf(xn[k], row[3 * k + 1], gg);
            go = fmaf(xn[k], row[3 * k + 2], go);
        }
        const float cn = sigmoid_pre(gi) * tanh_pre(gg);
        const float hn = sigmoid_pre(go) * tanh_(cn);

        lg[0] = fmaf(hn, row[117], lg[0]);
        lg[1] = fmaf(hn, row[118], lg[1]);
        lg[2] = fmaf(hn, row[119], lg[2]);
        lg[3] = fmaf(hn, row[120], lg[3]);
    }

    // ---- combine halves ----
#pragma unroll
    for (int k = 0; k < NCLS; ++k) lg[k] += __shfl_xor(lg[k], 1);

    // ================= log_softmax over 4 classes + store =================
    const float m = fmaxf(fmaxf(lg[0], lg[1]), fmaxf(lg[2], lg[3]));
    float s = 0.0f;
#pragma unroll
    for (int k = 0; k < NCLS; ++k) s += exp2_(L2E * (lg[k] - m));
    const float lse = __logf(s) + m;

    if (half == 0 && node < N) {
        float4 o4;
        o4.x = lg[0] - lse;
        o4.y = lg[1] - lse;
        o4.z = lg[2] - lse;
        o4.w = lg[3] - lse;
        *reinterpret_cast<float4*>(&out[node * NCLS]) = o4;
    }
}

extern "C" void kernel_launch(void* const* d_in, const int* in_sizes, int n_in,
                              void* d_out, int out_size, void* d_ws, size_t ws_size,
                              hipStream_t stream)
{
    // setup_inputs order:
    // 0 node_feat, 1 edge_feat, 2 src, 3 dst, 4 W_ih_n, 5 W_hh_n, 6 b_ih_n,
    // 7 b_hh_n, 8 W_ih_e, 9 W_hh_e, 10 b_ih_e, 11 b_hh_e, 12 W_nmpn,
    // 13 b_nmpn, 14 W_empn, 15 b_empn, 16 W_fc, 17 b_fc
    const float* node_feat = (const float*)d_in[0];
    const float* edge_feat = (const float*)d_in[1];
    const float* W_ih_n    = (const float*)d_in[4];
    const float* b_ih_n    = (const float*)d_in[6];
    const float* b_hh_n    = (const float*)d_in[7];
    const float* W_ih_e    = (const float*)d_in[8];
    const float* b_ih_e    = (const float*)d_in[10];
    const float* b_hh_e    = (const float*)d_in[11];
    const float* W_nmpn    = (const float*)d_in[12];
    const float* b_nmpn    = (const float*)d_in[13];
    const float* W_fc      = (const float*)d_in[16];
    const float* b_fc      = (const float*)d_in[17];
    float* out = (float*)d_out;

    const int N = in_sizes[0] / NIN;

    const int block = 512;                      // 256 nodes/block, 2 threads/node
    const int grid = (N + 256 - 1) / 256;       // 782 blocks
    fused_gnn_kernel<<<grid, block, 0, stream>>>(
        node_feat, edge_feat,
        W_ih_n, b_ih_n, b_hh_n,
        W_ih_e, b_ih_e, b_hh_e,
        W_nmpn, b_nmpn, W_fc, b_fc,
        out, N);
}

// Round 6
// 266.850 us; speedup vs baseline: 1.4781x; 1.4781x over previous
//
#include <hip/hip_runtime.h>

#define HID 128
#define NIN 21
#define EIN 2
#define NCLS 4

// LDS row layout (per hidden-dim d), stride 124 floats (496B = 31*16B, 16B-aligned):
//  [0..62]   node-gate weights interleaved as triples: (wi_k, wg_k, wo_k), k=0..20
//            wi,wo pre-scaled by L=log2(e); wg pre-scaled by 2L
//  [63..65]  combined node biases (same scaling): bi, bg, bo
//  [66..71]  edge weights (scaled): ewi0,ewi1, ewg0,ewg1, ewo0,ewo1
//  [72..74]  combined edge biases (scaled): ebi, ebg, ebo
//  [75..95]  L * W_nmpn[k][d]      (he coefficients), k=0..20
//  [96..116] L * W_nmpn[k][128+d]  (hn coefficients), k=0..20
//  [117..120] W_fc[c][d], c=0..3   (unscaled)
//
// PHYSICAL row interleave (bank-conflict fix): p(d) = 2*(d&63) + (d>>6).
// Lane pairs (2i,2i+1) process halves d and d+64 of the same node; with the
// interleave they read ADJACENT physical rows, address delta = 124 words
// == 28 mod 32 banks -> a b128 read uses banks {c..c+3} (even lanes) vs
// {c+28..c+31} (odd lanes): disjoint for all c. Round-5's non-interleaved
// layout had delta = 64 rows == 0 mod 32 banks -> 8.8e7 conflict cycles.
#define WSTRIDE 124

#define L2E   1.4426950408889634f   // log2(e)
#define L2E2  2.8853900817779268f   // 2*log2(e)

__device__ __forceinline__ float rcp_(float x) {
    return __builtin_amdgcn_rcpf(x);
}
__device__ __forceinline__ float exp2_(float x) {
    return __builtin_amdgcn_exp2f(x);
}
// input pre-scaled by L2E:  sigmoid(g) = 1/(1+2^(-g'))
__device__ __forceinline__ float sigmoid_pre(float gp) {
    return rcp_(1.0f + exp2_(-gp));
}
// input pre-scaled by 2*L2E: tanh(g) = 2/(1+2^(-g'')) - 1
__device__ __forceinline__ float tanh_pre(float gp) {
    return fmaf(2.0f, rcp_(1.0f + exp2_(-gp)), -1.0f);
}
// unscaled input
__device__ __forceinline__ float tanh_(float x) {
    return fmaf(2.0f, rcp_(1.0f + exp2_(-L2E2 * x)), -1.0f);
}

__global__ __launch_bounds__(512, 2)
void fused_gnn_kernel(const float* __restrict__ node_feat,  // N*21
                      const float* __restrict__ edge_feat,  // N*2
                      const float* __restrict__ W_ih_n,     // 512*21
                      const float* __restrict__ b_ih_n,     // 512
                      const float* __restrict__ b_hh_n,     // 512
                      const float* __restrict__ W_ih_e,     // 512*2
                      const float* __restrict__ b_ih_e,     // 512
                      const float* __restrict__ b_hh_e,     // 512
                      const float* __restrict__ W_nmpn,     // 21*256
                      const float* __restrict__ b_nmpn,     // 21
                      const float* __restrict__ W_fc,       // 4*128
                      const float* __restrict__ b_fc,       // 4
                      float* __restrict__ out,              // N*4
                      int N)
{
    __shared__ float lds[HID * WSTRIDE];   // 63488 B -> 2 blocks/CU -> 16 waves/CU

    const int tid = threadIdx.x;

    // ---------------- stage weights into LDS (once per block) ----------------
    if (tid < HID) {
        const int d = tid;
        float* row = &lds[(2 * (d & 63) + (d >> 6)) * WSTRIDE];
#pragma unroll
        for (int k = 0; k < NIN; ++k) {
            row[3 * k + 0] = L2E  * W_ih_n[(0 * HID + d) * NIN + k];
            row[3 * k + 1] = L2E2 * W_ih_n[(2 * HID + d) * NIN + k];
            row[3 * k + 2] = L2E  * W_ih_n[(3 * HID + d) * NIN + k];
        }
        row[63] = L2E  * (b_ih_n[0 * HID + d] + b_hh_n[0 * HID + d]);
        row[64] = L2E2 * (b_ih_n[2 * HID + d] + b_hh_n[2 * HID + d]);
        row[65] = L2E  * (b_ih_n[3 * HID + d] + b_hh_n[3 * HID + d]);
    } else if (tid < 2 * HID) {
        const int d = tid - HID;
        float* row = &lds[(2 * (d & 63) + (d >> 6)) * WSTRIDE];
        row[66] = L2E  * W_ih_e[(0 * HID + d) * EIN + 0];
        row[67] = L2E  * W_ih_e[(0 * HID + d) * EIN + 1];
        row[68] = L2E2 * W_ih_e[(2 * HID + d) * EIN + 0];
        row[69] = L2E2 * W_ih_e[(2 * HID + d) * EIN + 1];
        row[70] = L2E  * W_ih_e[(3 * HID + d) * EIN + 0];
        row[71] = L2E  * W_ih_e[(3 * HID + d) * EIN + 1];
        row[72] = L2E  * (b_ih_e[0 * HID + d] + b_hh_e[0 * HID + d]);
        row[73] = L2E2 * (b_ih_e[2 * HID + d] + b_hh_e[2 * HID + d]);
        row[74] = L2E  * (b_ih_e[3 * HID + d] + b_hh_e[3 * HID + d]);
#pragma unroll
        for (int k = 0; k < NIN; ++k) {
            row[75 + k] = L2E * W_nmpn[k * 2 * HID + d];
            row[96 + k] = L2E * W_nmpn[k * 2 * HID + HID + d];
        }
#pragma unroll
        for (int c = 0; c < NCLS; ++c) {
            row[117 + c] = W_fc[c * HID + d];
        }
    }
    __syncthreads();

    // ---------------- node assignment: 2 threads per node ----------------
    const int half = tid & 1;                         // d-range half
    const int node = blockIdx.x * 256 + (tid >> 1);   // 256 nodes per block
    const int nidx = (node < N) ? node : (N - 1);

    float xn[NIN];
#pragma unroll
    for (int k = 0; k < NIN; ++k) xn[k] = node_feat[nidx * NIN + k];
    const float xe0 = edge_feat[nidx * EIN + 0];
    const float xe1 = edge_feat[nidx * EIN + 1];

    float acc[NIN];   // partial: L2E * (xn1 pre-activation), this half's d-sum
#pragma unroll
    for (int k = 0; k < NIN; ++k) acc[k] = half ? 0.0f : (L2E * b_nmpn[k]);
    float lg[NCLS];
#pragma unroll
    for (int k = 0; k < NCLS; ++k) lg[k] = half ? 0.0f : b_fc[k];

    // ================= iteration 1 (64 d's per thread) =================
#pragma unroll 2
    for (int dd = 0; dd < 64; ++dd) {
        const float* row = &lds[(2 * dd + half) * WSTRIDE];

        float gi = row[63], gg = row[64], go = row[65];
#pragma unroll
        for (int k = 0; k < NIN; ++k) {
            gi = fmaf(xn[k], row[3 * k + 0], gi);
            gg = fmaf(xn[k], row[3 * k + 1], gg);
            go = fmaf(xn[k], row[3 * k + 2], go);
        }
        const float cn = sigmoid_pre(gi) * tanh_pre(gg);
        const float hn = sigmoid_pre(go) * tanh_(cn);

        const float ei = fmaf(xe0, row[66], fmaf(xe1, row[67], row[72]));
        const float eg = fmaf(xe0, row[68], fmaf(xe1, row[69], row[73]));
        const float eo = fmaf(xe0, row[70], fmaf(xe1, row[71], row[74]));
        const float ce = sigmoid_pre(ei) * tanh_pre(eg);
        const float he = sigmoid_pre(eo) * tanh_(ce);

#pragma unroll
        for (int k = 0; k < NIN; ++k) {
            acc[k] = fmaf(he, row[75 + k], fmaf(hn, row[96 + k], acc[k]));
        }
    }

    // ---- combine halves (lane pair 2i <-> 2i+1), both lanes get full sum ----
#pragma unroll
    for (int k = 0; k < NIN; ++k) {
        acc[k] += __shfl_xor(acc[k], 1);
        xn[k] = sigmoid_pre(acc[k]);
    }

    // ================= iteration 2 (only h_n matters) =================
#pragma unroll 2
    for (int dd = 0; dd < 64; ++dd) {
        const float* row = &lds[(2 * dd + half) * WSTRIDE];

        float gi = row[63], gg = row[64], go = row[65];
#pragma unroll
        for (int k = 0; k < NIN; ++k) {
            gi = fmaf(xn[k], row[3 * k + 0], gi);
            gg = fmaf(xn[k], row[3 * k + 1], gg);
            go = fmaf(xn[k], row[3 * k + 2], go);
        }
        const float cn = sigmoid_pre(gi) * tanh_pre(gg);
        const float hn = sigmoid_pre(go) * tanh_(cn);

        lg[0] = fmaf(hn, row[117], lg[0]);
        lg[1] = fmaf(hn, row[118], lg[1]);
        lg[2] = fmaf(hn, row[119], lg[2]);
        lg[3] = fmaf(hn, row[120], lg[3]);
    }

    // ---- combine halves ----
#pragma unroll
    for (int k = 0; k < NCLS; ++k) lg[k] += __shfl_xor(lg[k], 1);

    // ================= log_softmax over 4 classes + store =================
    const float m = fmaxf(fmaxf(lg[0], lg[1]), fmaxf(lg[2], lg[3]));
    float s = 0.0f;
#pragma unroll
    for (int k = 0; k < NCLS; ++k) s += exp2_(L2E * (lg[k] - m));
    const float lse = __logf(s) + m;

    if (half == 0 && node < N) {
        float4 o4;
        o4.x = lg[0] - lse;
        o4.y = lg[1] - lse;
        o4.z = lg[2] - lse;
        o4.w = lg[3] - lse;
        *reinterpret_cast<float4*>(&out[node * NCLS]) = o4;
    }
}

extern "C" void kernel_launch(void* const* d_in, const int* in_sizes, int n_in,
                              void* d_out, int out_size, void* d_ws, size_t ws_size,
                              hipStream_t stream)
{
    // setup_inputs order:
    // 0 node_feat, 1 edge_feat, 2 src, 3 dst, 4 W_ih_n, 5 W_hh_n, 6 b_ih_n,
    // 7 b_hh_n, 8 W_ih_e, 9 W_hh_e, 10 b_ih_e, 11 b_hh_e, 12 W_nmpn,
    // 13 b_nmpn, 14 W_empn, 15 b_empn, 16 W_fc, 17 b_fc
    const float* node_feat = (const float*)d_in[0];
    const float* edge_feat = (const float*)d_in[1];
    const float* W_ih_n    = (const float*)d_in[4];
    const float* b_ih_n    = (const float*)d_in[6];
    const float* b_hh_n    = (const float*)d_in[7];
    const float* W_ih_e    = (const float*)d_in[8];
    const float* b_ih_e    = (const float*)d_in[10];
    const float* b_hh_e    = (const float*)d_in[11];
    const float* W_nmpn    = (const float*)d_in[12];
    const float* b_nmpn    = (const float*)d_in[13];
    const float* W_fc      = (const float*)d_in[16];
    const float* b_fc      = (const float*)d_in[17];
    float* out = (float*)d_out;

    const int N = in_sizes[0] / NIN;

    const int block = 512;                      // 256 nodes/block, 2 threads/node
    const int grid = (N + 256 - 1) / 256;       // 782 blocks
    fused_gnn_kernel<<<grid, block, 0, stream>>>(
        node_feat, edge_feat,
        W_ih_n, b_ih_n, b_hh_n,
        W_ih_e, b_ih_e, b_hh_e,
        W_nmpn, b_nmpn, W_fc, b_fc,
        out, N);
}

// Round 7
// 180.954 us; speedup vs baseline: 2.1797x; 1.4747x over previous
//
#include <hip/hip_runtime.h>

#define HID 128
#define NIN 21
#define EIN 2
#define NCLS 4

// ---------------- LDS row layout (per hidden-dim d) ----------------
// Units: u32 words. Row stride 68 u32 = 272 B (16B-aligned). Total 128*272 = 34816 B.
//  [0..10]   gi weight pairs  (f16x2): (w[2j], w[2j+1]), j=10 -> (w[20], 0).  scaled by L2E
//  [11..21]  gg weight pairs, scaled by 2*L2E
//  [22..32]  go weight pairs, scaled by L2E
//  [33..53]  nmpn pairs k=0..20: (L2E*W_nmpn[k][d], L2E*W_nmpn[k][128+d])  -> dots with (he,hn)
//  [54..56]  edge gate pairs (i,g,o): (s*We[g][d][0], s*We[g][d][1]) -> dots with (xe0,xe1)
//  [57..59]  f32 node biases  bi, bg, bo   (b_ih+b_hh, scaled)
//  [60..62]  f32 edge biases  ebi, ebg, ebo (scaled)
//  [63..66]  f32 W_fc[c][d]
//  [67]      pad
// All lanes of a wave read the SAME row (uniform broadcast -> no bank conflicts).
#define WSTRIDE 68

#define L2E   1.4426950408889634f   // log2(e)
#define L2E2  2.8853900817779268f   // 2*log2(e)

typedef _Float16 h2_t __attribute__((ext_vector_type(2)));

__device__ __forceinline__ unsigned pack_f16(float a, float b) {
    h2_t h;
    h.x = (_Float16)a;
    h.y = (_Float16)b;
    return __builtin_bit_cast(unsigned, h);
}

__device__ __forceinline__ float fdot2_(unsigned a, unsigned b, float c) {
#if __has_builtin(__builtin_amdgcn_fdot2)
    return __builtin_amdgcn_fdot2(__builtin_bit_cast(h2_t, a),
                                  __builtin_bit_cast(h2_t, b), c, false);
#else
    h2_t ha = __builtin_bit_cast(h2_t, a), hb = __builtin_bit_cast(h2_t, b);
    return fmaf((float)ha.x, (float)hb.x, fmaf((float)ha.y, (float)hb.y, c));
#endif
}

__device__ __forceinline__ float rcp_(float x)  { return __builtin_amdgcn_rcpf(x); }
__device__ __forceinline__ float exp2_(float x) { return __builtin_amdgcn_exp2f(x); }
// input pre-scaled by L2E:  sigmoid(g) = 1/(1+2^(-g'))
__device__ __forceinline__ float sigmoid_pre(float gp) { return rcp_(1.0f + exp2_(-gp)); }
// input pre-scaled by 2*L2E: tanh(g) = 2/(1+2^(-g'')) - 1
__device__ __forceinline__ float tanh_pre(float gp) { return fmaf(2.0f, rcp_(1.0f + exp2_(-gp)), -1.0f); }
// unscaled input
__device__ __forceinline__ float tanh_(float x) { return fmaf(2.0f, rcp_(1.0f + exp2_(-L2E2 * x)), -1.0f); }

__global__ __launch_bounds__(256, 4)
void fused_gnn_kernel(const float* __restrict__ node_feat,  // N*21
                      const float* __restrict__ edge_feat,  // N*2
                      const float* __restrict__ W_ih_n,     // 512*21
                      const float* __restrict__ b_ih_n,     // 512
                      const float* __restrict__ b_hh_n,     // 512
                      const float* __restrict__ W_ih_e,     // 512*2
                      const float* __restrict__ b_ih_e,     // 512
                      const float* __restrict__ b_hh_e,     // 512
                      const float* __restrict__ W_nmpn,     // 21*256
                      const float* __restrict__ b_nmpn,     // 21
                      const float* __restrict__ W_fc,       // 4*128
                      const float* __restrict__ b_fc,       // 4
                      float* __restrict__ out,              // N*4
                      int N)
{
    __shared__ unsigned ldsu[HID * WSTRIDE];   // 34816 B -> 4 blocks/CU

    const int tid = threadIdx.x;

    // ---------------- stage weight table (once per block) ----------------
    if (tid < HID) {
        const int d = tid;
        unsigned* row = &ldsu[d * WSTRIDE];
        const float* wi = &W_ih_n[(0 * HID + d) * NIN];
        const float* wg = &W_ih_n[(2 * HID + d) * NIN];
        const float* wo = &W_ih_n[(3 * HID + d) * NIN];
#pragma unroll
        for (int j = 0; j < 10; ++j) {
            row[j]      = pack_f16(L2E  * wi[2 * j], L2E  * wi[2 * j + 1]);
            row[11 + j] = pack_f16(L2E2 * wg[2 * j], L2E2 * wg[2 * j + 1]);
            row[22 + j] = pack_f16(L2E  * wo[2 * j], L2E  * wo[2 * j + 1]);
        }
        row[10] = pack_f16(L2E  * wi[20], 0.0f);
        row[21] = pack_f16(L2E2 * wg[20], 0.0f);
        row[32] = pack_f16(L2E  * wo[20], 0.0f);
        row[57] = __float_as_uint(L2E  * (b_ih_n[0 * HID + d] + b_hh_n[0 * HID + d]));
        row[58] = __float_as_uint(L2E2 * (b_ih_n[2 * HID + d] + b_hh_n[2 * HID + d]));
        row[59] = __float_as_uint(L2E  * (b_ih_n[3 * HID + d] + b_hh_n[3 * HID + d]));
    } else {
        const int d = tid - HID;
        unsigned* row = &ldsu[d * WSTRIDE];
#pragma unroll
        for (int k = 0; k < NIN; ++k) {
            row[33 + k] = pack_f16(L2E * W_nmpn[k * 2 * HID + d],
                                   L2E * W_nmpn[k * 2 * HID + HID + d]);
        }
        row[54] = pack_f16(L2E  * W_ih_e[(0 * HID + d) * EIN + 0],
                           L2E  * W_ih_e[(0 * HID + d) * EIN + 1]);
        row[55] = pack_f16(L2E2 * W_ih_e[(2 * HID + d) * EIN + 0],
                           L2E2 * W_ih_e[(2 * HID + d) * EIN + 1]);
        row[56] = pack_f16(L2E  * W_ih_e[(3 * HID + d) * EIN + 0],
                           L2E  * W_ih_e[(3 * HID + d) * EIN + 1]);
        row[60] = __float_as_uint(L2E  * (b_ih_e[0 * HID + d] + b_hh_e[0 * HID + d]));
        row[61] = __float_as_uint(L2E2 * (b_ih_e[2 * HID + d] + b_hh_e[2 * HID + d]));
        row[62] = __float_as_uint(L2E  * (b_ih_e[3 * HID + d] + b_hh_e[3 * HID + d]));
#pragma unroll
        for (int c = 0; c < NCLS; ++c) row[63 + c] = __float_as_uint(W_fc[c * HID + d]);
    }
    __syncthreads();

    // ---------------- per-node inputs ----------------
    const int n = blockIdx.x * blockDim.x + tid;
    const int nidx = (n < N) ? n : (N - 1);

    unsigned xnp[11];   // node input as f16 pairs
    {
#pragma unroll
        for (int j = 0; j < 10; ++j)
            xnp[j] = pack_f16(node_feat[nidx * NIN + 2 * j], node_feat[nidx * NIN + 2 * j + 1]);
        xnp[10] = pack_f16(node_feat[nidx * NIN + 20], 0.0f);
    }
    const unsigned xep = pack_f16(edge_feat[nidx * EIN + 0], edge_feat[nidx * EIN + 1]);

    float acc[NIN];   // L2E * xn1 pre-activation
#pragma unroll
    for (int k = 0; k < NIN; ++k) acc[k] = L2E * b_nmpn[k];
    float lg[NCLS];
#pragma unroll
    for (int k = 0; k < NCLS; ++k) lg[k] = b_fc[k];

    // ================= iteration 1 =================
#pragma unroll 2
    for (int d = 0; d < HID; ++d) {
        const unsigned* row = &ldsu[d * WSTRIDE];

        float gi = __uint_as_float(row[57]);
        float gg = __uint_as_float(row[58]);
        float go = __uint_as_float(row[59]);
#pragma unroll
        for (int j = 0; j < 11; ++j) {
            gi = fdot2_(xnp[j], row[j],      gi);
            gg = fdot2_(xnp[j], row[11 + j], gg);
            go = fdot2_(xnp[j], row[22 + j], go);
        }
        const float cn = sigmoid_pre(gi) * tanh_pre(gg);
        const float hn = sigmoid_pre(go) * tanh_(cn);

        const float ei = fdot2_(xep, row[54], __uint_as_float(row[60]));
        const float eg = fdot2_(xep, row[55], __uint_as_float(row[61]));
        const float eo = fdot2_(xep, row[56], __uint_as_float(row[62]));
        const float ce = sigmoid_pre(ei) * tanh_pre(eg);
        const float he = sigmoid_pre(eo) * tanh_(ce);

        const unsigned hp = pack_f16(he, hn);
#pragma unroll
        for (int k = 0; k < NIN; ++k) acc[k] = fdot2_(hp, row[33 + k], acc[k]);
    }

    // xn1 = sigmoid(pre) -> repack as f16 pairs
    {
        float x[NIN];
#pragma unroll
        for (int k = 0; k < NIN; ++k) x[k] = sigmoid_pre(acc[k]);
#pragma unroll
        for (int j = 0; j < 10; ++j) xnp[j] = pack_f16(x[2 * j], x[2 * j + 1]);
        xnp[10] = pack_f16(x[20], 0.0f);
    }

    // ================= iteration 2 (only h_n matters) =================
#pragma unroll 2
    for (int d = 0; d < HID; ++d) {
        const unsigned* row = &ldsu[d * WSTRIDE];

        float gi = __uint_as_float(row[57]);
        float gg = __uint_as_float(row[58]);
        float go = __uint_as_float(row[59]);
#pragma unroll
        for (int j = 0; j < 11; ++j) {
            gi = fdot2_(xnp[j], row[j],      gi);
            gg = fdot2_(xnp[j], row[11 + j], gg);
            go = fdot2_(xnp[j], row[22 + j], go);
        }
        const float cn = sigmoid_pre(gi) * tanh_pre(gg);
        const float hn = sigmoid_pre(go) * tanh_(cn);

        lg[0] = fmaf(hn, __uint_as_float(row[63]), lg[0]);
        lg[1] = fmaf(hn, __uint_as_float(row[64]), lg[1]);
        lg[2] = fmaf(hn, __uint_as_float(row[65]), lg[2]);
        lg[3] = fmaf(hn, __uint_as_float(row[66]), lg[3]);
    }

    // ================= log_softmax over 4 classes + store =================
    const float m = fmaxf(fmaxf(lg[0], lg[1]), fmaxf(lg[2], lg[3]));
    float s = 0.0f;
#pragma unroll
    for (int k = 0; k < NCLS; ++k) s += exp2_(L2E * (lg[k] - m));
    const float lse = __logf(s) + m;

    if (n < N) {
        float4 o4;
        o4.x = lg[0] - lse;
        o4.y = lg[1] - lse;
        o4.z = lg[2] - lse;
        o4.w = lg[3] - lse;
        *reinterpret_cast<float4*>(&out[n * NCLS]) = o4;
    }
}

extern "C" void kernel_launch(void* const* d_in, const int* in_sizes, int n_in,
                              void* d_out, int out_size, void* d_ws, size_t ws_size,
                              hipStream_t stream)
{
    // setup_inputs order:
    // 0 node_feat, 1 edge_feat, 2 src, 3 dst, 4 W_ih_n, 5 W_hh_n, 6 b_ih_n,
    // 7 b_hh_n, 8 W_ih_e, 9 W_hh_e, 10 b_ih_e, 11 b_hh_e, 12 W_nmpn,
    // 13 b_nmpn, 14 W_empn, 15 b_empn, 16 W_fc, 17 b_fc
    const float* node_feat = (const float*)d_in[0];
    const float* edge_feat = (const float*)d_in[1];
    const float* W_ih_n    = (const float*)d_in[4];
    const float* b_ih_n    = (const float*)d_in[6];
    const float* b_hh_n    = (const float*)d_in[7];
    const float* W_ih_e    = (const float*)d_in[8];
    const float* b_ih_e    = (const float*)d_in[10];
    const float* b_hh_e    = (const float*)d_in[11];
    const float* W_nmpn    = (const float*)d_in[12];
    const float* b_nmpn    = (const float*)d_in[13];
    const float* W_fc      = (const float*)d_in[16];
    const float* b_fc      = (const float*)d_in[17];
    float* out = (float*)d_out;

    const int N = in_sizes[0] / NIN;

    const int block = 256;                 // 4 waves/block; 34.8KB LDS -> up to 4 blocks/CU
    const int grid = (N + block - 1) / block;   // 782
    fused_gnn_kernel<<<grid, block, 0, stream>>>(
        node_feat, edge_feat,
        W_ih_n, b_ih_n, b_hh_n,
        W_ih_e, b_ih_e, b_hh_e,
        W_nmpn, b_nmpn, W_fc, b_fc,
        out, N);
}

// Round 8
// 179.560 us; speedup vs baseline: 2.1967x; 1.0078x over previous
//
#include <hip/hip_runtime.h>

#define HID 128
#define NIN 21
#define EIN 2
#define NCLS 4

// ---------------- LDS row layout (per hidden-dim d) ----------------
// Units: u32 words. Row stride 68 u32 = 272 B (16B-aligned). Total 128*272 = 34816 B.
//  [0..10]   gi weight pairs  (f16x2): (w[2j], w[2j+1]), j=10 -> (w[20], 0).  scaled by L2E
//  [11..21]  gg weight pairs, scaled by 2*L2E
//  [22..32]  go weight pairs, scaled by L2E
//  [33..53]  nmpn pairs k=0..20: (L2E*W_nmpn[k][d], L2E*W_nmpn[k][128+d])  -> dots with (he,hn)
//  [54..56]  edge gate pairs (i,g,o): (s*We[g][d][0], s*We[g][d][1]) -> dots with (xe0,xe1)
//  [57..59]  f32 node biases  bi, bg, bo   (b_ih+b_hh, scaled)
//  [60..62]  f32 edge biases  ebi, ebg, ebo (scaled)
//  [63..66]  f32 W_fc[c][d]
//  [67]      pad
// All lanes of a wave read the SAME row (uniform broadcast -> no bank conflicts).
#define WSTRIDE 68

#define L2E   1.4426950408889634f   // log2(e)
#define L2E2  2.8853900817779268f   // 2*log2(e)

typedef _Float16 h2_t __attribute__((ext_vector_type(2)));

__device__ __forceinline__ unsigned pack_f16(float a, float b) {
    h2_t h;
    h.x = (_Float16)a;
    h.y = (_Float16)b;
    return __builtin_bit_cast(unsigned, h);
}

__device__ __forceinline__ float fdot2_(unsigned a, unsigned b, float c) {
#if __has_builtin(__builtin_amdgcn_fdot2)
    return __builtin_amdgcn_fdot2(__builtin_bit_cast(h2_t, a),
                                  __builtin_bit_cast(h2_t, b), c, false);
#else
    h2_t ha = __builtin_bit_cast(h2_t, a), hb = __builtin_bit_cast(h2_t, b);
    return fmaf((float)ha.x, (float)hb.x, fmaf((float)ha.y, (float)hb.y, c));
#endif
}

__device__ __forceinline__ float rcp_(float x)  { return __builtin_amdgcn_rcpf(x); }
__device__ __forceinline__ float exp2_(float x) { return __builtin_amdgcn_exp2f(x); }
// input pre-scaled by L2E:  sigmoid(g) = 1/(1+2^(-g'))
__device__ __forceinline__ float sigmoid_pre(float gp) { return rcp_(1.0f + exp2_(-gp)); }
// input pre-scaled by 2*L2E: tanh(g) = 2/(1+2^(-g'')) - 1
__device__ __forceinline__ float tanh_pre(float gp) { return fmaf(2.0f, rcp_(1.0f + exp2_(-gp)), -1.0f); }
// unscaled input
__device__ __forceinline__ float tanh_(float x) { return fmaf(2.0f, rcp_(1.0f + exp2_(-L2E2 * x)), -1.0f); }

// (256,2): VGPR ceiling 256 — session empirics: min_waves=4 makes the compiler
// pick 64 VGPR and spill ~7MB/launch (rounds 4,7); (256,2) lands ~128, no spill
// (round 3). 128 VGPR -> 4 waves/SIMD -> 16 waves/CU = 4 blocks/CU, which
// exactly matches the LDS cap (4 x 34.8KB = 139KB < 160KB).
__global__ __launch_bounds__(256, 2)
void fused_gnn_kernel(const float* __restrict__ node_feat,  // N*21
                      const float* __restrict__ edge_feat,  // N*2
                      const float* __restrict__ W_ih_n,     // 512*21
                      const float* __restrict__ b_ih_n,     // 512
                      const float* __restrict__ b_hh_n,     // 512
                      const float* __restrict__ W_ih_e,     // 512*2
                      const float* __restrict__ b_ih_e,     // 512
                      const float* __restrict__ b_hh_e,     // 512
                      const float* __restrict__ W_nmpn,     // 21*256
                      const float* __restrict__ b_nmpn,     // 21
                      const float* __restrict__ W_fc,       // 4*128
                      const float* __restrict__ b_fc,       // 4
                      float* __restrict__ out,              // N*4
                      int N)
{
    __shared__ unsigned ldsu[HID * WSTRIDE];   // 34816 B -> 4 blocks/CU

    const int tid = threadIdx.x;

    // ---------------- stage weight table (once per block) ----------------
    if (tid < HID) {
        const int d = tid;
        unsigned* row = &ldsu[d * WSTRIDE];
        const float* wi = &W_ih_n[(0 * HID + d) * NIN];
        const float* wg = &W_ih_n[(2 * HID + d) * NIN];
        const float* wo = &W_ih_n[(3 * HID + d) * NIN];
#pragma unroll
        for (int j = 0; j < 10; ++j) {
            row[j]      = pack_f16(L2E  * wi[2 * j], L2E  * wi[2 * j + 1]);
            row[11 + j] = pack_f16(L2E2 * wg[2 * j], L2E2 * wg[2 * j + 1]);
            row[22 + j] = pack_f16(L2E  * wo[2 * j], L2E  * wo[2 * j + 1]);
        }
        row[10] = pack_f16(L2E  * wi[20], 0.0f);
        row[21] = pack_f16(L2E2 * wg[20], 0.0f);
        row[32] = pack_f16(L2E  * wo[20], 0.0f);
        row[57] = __float_as_uint(L2E  * (b_ih_n[0 * HID + d] + b_hh_n[0 * HID + d]));
        row[58] = __float_as_uint(L2E2 * (b_ih_n[2 * HID + d] + b_hh_n[2 * HID + d]));
        row[59] = __float_as_uint(L2E  * (b_ih_n[3 * HID + d] + b_hh_n[3 * HID + d]));
    } else {
        const int d = tid - HID;
        unsigned* row = &ldsu[d * WSTRIDE];
#pragma unroll
        for (int k = 0; k < NIN; ++k) {
            row[33 + k] = pack_f16(L2E * W_nmpn[k * 2 * HID + d],
                                   L2E * W_nmpn[k * 2 * HID + HID + d]);
        }
        row[54] = pack_f16(L2E  * W_ih_e[(0 * HID + d) * EIN + 0],
                           L2E  * W_ih_e[(0 * HID + d) * EIN + 1]);
        row[55] = pack_f16(L2E2 * W_ih_e[(2 * HID + d) * EIN + 0],
                           L2E2 * W_ih_e[(2 * HID + d) * EIN + 1]);
        row[56] = pack_f16(L2E  * W_ih_e[(3 * HID + d) * EIN + 0],
                           L2E  * W_ih_e[(3 * HID + d) * EIN + 1]);
        row[60] = __float_as_uint(L2E  * (b_ih_e[0 * HID + d] + b_hh_e[0 * HID + d]));
        row[61] = __float_as_uint(L2E2 * (b_ih_e[2 * HID + d] + b_hh_e[2 * HID + d]));
        row[62] = __float_as_uint(L2E  * (b_ih_e[3 * HID + d] + b_hh_e[3 * HID + d]));
#pragma unroll
        for (int c = 0; c < NCLS; ++c) row[63 + c] = __float_as_uint(W_fc[c * HID + d]);
    }
    __syncthreads();

    // ---------------- per-node inputs ----------------
    const int n = blockIdx.x * blockDim.x + tid;
    const int nidx = (n < N) ? n : (N - 1);

    unsigned xnp[11];   // node input as f16 pairs
    {
#pragma unroll
        for (int j = 0; j < 10; ++j)
            xnp[j] = pack_f16(node_feat[nidx * NIN + 2 * j], node_feat[nidx * NIN + 2 * j + 1]);
        xnp[10] = pack_f16(node_feat[nidx * NIN + 20], 0.0f);
    }
    const unsigned xep = pack_f16(edge_feat[nidx * EIN + 0], edge_feat[nidx * EIN + 1]);

    float acc[NIN];   // L2E * xn1 pre-activation
#pragma unroll
    for (int k = 0; k < NIN; ++k) acc[k] = L2E * b_nmpn[k];
    float lg[NCLS];
#pragma unroll
    for (int k = 0; k < NCLS; ++k) lg[k] = b_fc[k];

    // ================= iteration 1 =================
#pragma unroll 2
    for (int d = 0; d < HID; ++d) {
        const unsigned* row = &ldsu[d * WSTRIDE];

        float gi = __uint_as_float(row[57]);
        float gg = __uint_as_float(row[58]);
        float go = __uint_as_float(row[59]);
#pragma unroll
        for (int j = 0; j < 11; ++j) {
            gi = fdot2_(xnp[j], row[j],      gi);
            gg = fdot2_(xnp[j], row[11 + j], gg);
            go = fdot2_(xnp[j], row[22 + j], go);
        }
        const float cn = sigmoid_pre(gi) * tanh_pre(gg);
        const float hn = sigmoid_pre(go) * tanh_(cn);

        const float ei = fdot2_(xep, row[54], __uint_as_float(row[60]));
        const float eg = fdot2_(xep, row[55], __uint_as_float(row[61]));
        const float eo = fdot2_(xep, row[56], __uint_as_float(row[62]));
        const float ce = sigmoid_pre(ei) * tanh_pre(eg);
        const float he = sigmoid_pre(eo) * tanh_(ce);

        const unsigned hp = pack_f16(he, hn);
#pragma unroll
        for (int k = 0; k < NIN; ++k) acc[k] = fdot2_(hp, row[33 + k], acc[k]);
    }

    // xn1 = sigmoid(pre) -> repack as f16 pairs
    {
        float x[NIN];
#pragma unroll
        for (int k = 0; k < NIN; ++k) x[k] = sigmoid_pre(acc[k]);
#pragma unroll
        for (int j = 0; j < 10; ++j) xnp[j] = pack_f16(x[2 * j], x[2 * j + 1]);
        xnp[10] = pack_f16(x[20], 0.0f);
    }

    // ================= iteration 2 (only h_n matters) =================
#pragma unroll 2
    for (int d = 0; d < HID; ++d) {
        const unsigned* row = &ldsu[d * WSTRIDE];

        float gi = __uint_as_float(row[57]);
        float gg = __uint_as_float(row[58]);
        float go = __uint_as_float(row[59]);
#pragma unroll
        for (int j = 0; j < 11; ++j) {
            gi = fdot2_(xnp[j], row[j],      gi);
            gg = fdot2_(xnp[j], row[11 + j], gg);
            go = fdot2_(xnp[j], row[22 + j], go);
        }
        const float cn = sigmoid_pre(gi) * tanh_pre(gg);
        const float hn = sigmoid_pre(go) * tanh_(cn);

        lg[0] = fmaf(hn, __uint_as_float(row[63]), lg[0]);
        lg[1] = fmaf(hn, __uint_as_float(row[64]), lg[1]);
        lg[2] = fmaf(hn, __uint_as_float(row[65]), lg[2]);
        lg[3] = fmaf(hn, __uint_as_float(row[66]), lg[3]);
    }

    // ================= log_softmax over 4 classes + store =================
    const float m = fmaxf(fmaxf(lg[0], lg[1]), fmaxf(lg[2], lg[3]));
    float s = 0.0f;
#pragma unroll
    for (int k = 0; k < NCLS; ++k) s += exp2_(L2E * (lg[k] - m));
    const float lse = __logf(s) + m;

    if (n < N) {
        float4 o4;
        o4.x = lg[0] - lse;
        o4.y = lg[1] - lse;
        o4.z = lg[2] - lse;
        o4.w = lg[3] - lse;
        *reinterpret_cast<float4*>(&out[n * NCLS]) = o4;
    }
}

extern "C" void kernel_launch(void* const* d_in, const int* in_sizes, int n_in,
                              void* d_out, int out_size, void* d_ws, size_t ws_size,
                              hipStream_t stream)
{
    // setup_inputs order:
    // 0 node_feat, 1 edge_feat, 2 src, 3 dst, 4 W_ih_n, 5 W_hh_n, 6 b_ih_n,
    // 7 b_hh_n, 8 W_ih_e, 9 W_hh_e, 10 b_ih_e, 11 b_hh_e, 12 W_nmpn,
    // 13 b_nmpn, 14 W_empn, 15 b_empn, 16 W_fc, 17 b_fc
    const float* node_feat = (const float*)d_in[0];
    const float* edge_feat = (const float*)d_in[1];
    const float* W_ih_n    = (const float*)d_in[4];
    const float* b_ih_n    = (const float*)d_in[6];
    const float* b_hh_n    = (const float*)d_in[7];
    const float* W_ih_e    = (const float*)d_in[8];
    const float* b_ih_e    = (const float*)d_in[10];
    const float* b_hh_e    = (const float*)d_in[11];
    const float* W_nmpn    = (const float*)d_in[12];
    const float* b_nmpn    = (const float*)d_in[13];
    const float* W_fc      = (const float*)d_in[16];
    const float* b_fc      = (const float*)d_in[17];
    float* out = (float*)d_out;

    const int N = in_sizes[0] / NIN;

    const int block = 256;                 // 4 waves/block; 34.8KB LDS -> up to 4 blocks/CU
    const int grid = (N + block - 1) / block;   // 782
    fused_gnn_kernel<<<grid, block, 0, stream>>>(
        node_feat, edge_feat,
        W_ih_n, b_ih_n, b_hh_n,
        W_ih_e, b_ih_e, b_hh_e,
        W_nmpn, b_nmpn, W_fc, b_fc,
        out, N);
}

// Round 9
// 174.345 us; speedup vs baseline: 2.2624x; 1.0299x over previous
//
#include <hip/hip_runtime.h>

#define HID 128
#define NIN 21
#define EIN 2
#define NCLS 4

// ---------------- LDS row layout (per hidden-dim d) ----------------
// Units: u32 words. Row stride 68 u32 = 272 B (16B-aligned). Total 128*272 = 34816 B.
//  [0..10]   gi weight pairs  (f16x2), scaled by L2E
//  [11..21]  gg weight pairs, scaled by 2*L2E
//  [22..32]  go weight pairs, scaled by L2E
//  [33..53]  nmpn pairs k=0..20: (L2E*W_nmpn[k][d], L2E*W_nmpn[k][128+d]) -> dot with (he,hn)
//  [54..56]  edge gate pairs (i,g,o)
//  [57..59]  f32 node biases  bi, bg, bo (scaled)
//  [60..62]  f32 edge biases (scaled)
//  [63..66]  f32 W_fc[c][d]
//  [67]      pad
// All lanes of a wave read the SAME row (uniform broadcast). NPT=2: both of a
// thread's nodes share every weight word -> LDS reads per node HALVED vs r8.
#define WSTRIDE 68

#define L2E   1.4426950408889634f   // log2(e)
#define L2E2  2.8853900817779268f   // 2*log2(e)

typedef _Float16 h2_t __attribute__((ext_vector_type(2)));

__device__ __forceinline__ unsigned pack_f16(float a, float b) {
    h2_t h;
    h.x = (_Float16)a;
    h.y = (_Float16)b;
    return __builtin_bit_cast(unsigned, h);
}

__device__ __forceinline__ float fdot2_(unsigned a, unsigned b, float c) {
#if __has_builtin(__builtin_amdgcn_fdot2)
    return __builtin_amdgcn_fdot2(__builtin_bit_cast(h2_t, a),
                                  __builtin_bit_cast(h2_t, b), c, false);
#else
    h2_t ha = __builtin_bit_cast(h2_t, a), hb = __builtin_bit_cast(h2_t, b);
    return fmaf((float)ha.x, (float)hb.x, fmaf((float)ha.y, (float)hb.y, c));
#endif
}

__device__ __forceinline__ float rcp_(float x)  { return __builtin_amdgcn_rcpf(x); }
__device__ __forceinline__ float exp2_(float x) { return __builtin_amdgcn_exp2f(x); }
__device__ __forceinline__ float sigmoid_pre(float gp) { return rcp_(1.0f + exp2_(-gp)); }
__device__ __forceinline__ float tanh_pre(float gp) { return fmaf(2.0f, rcp_(1.0f + exp2_(-gp)), -1.0f); }
__device__ __forceinline__ float tanh_(float x) { return fmaf(2.0f, rcp_(1.0f + exp2_(-L2E2 * x)), -1.0f); }

// block=128 (2 waves), 2 nodes/thread -> 256 nodes/block, grid 782.
// (128,2): VGPR ceiling 256 -> room for ~110-130 live regs, no spill.
__global__ __launch_bounds__(128, 2)
void fused_gnn_kernel(const float* __restrict__ node_feat,  // N*21
                      const float* __restrict__ edge_feat,  // N*2
                      const float* __restrict__ W_ih_n,     // 512*21
                      const float* __restrict__ b_ih_n,     // 512
                      const float* __restrict__ b_hh_n,     // 512
                      const float* __restrict__ W_ih_e,     // 512*2
                      const float* __restrict__ b_ih_e,     // 512
                      const float* __restrict__ b_hh_e,     // 512
                      const float* __restrict__ W_nmpn,     // 21*256
                      const float* __restrict__ b_nmpn,     // 21
                      const float* __restrict__ W_fc,       // 4*128
                      const float* __restrict__ b_fc,       // 4
                      float* __restrict__ out,              // N*4
                      int N)
{
    __shared__ unsigned ldsu[HID * WSTRIDE];   // 34816 B -> 4 blocks/CU cap

    const int tid = threadIdx.x;

    // ---------------- stage weight table (once per block, 2 passes) ----------------
    for (int t = tid; t < 2 * HID; t += 128) {
        if (t < HID) {
            const int d = t;
            unsigned* row = &ldsu[d * WSTRIDE];
            const float* wi = &W_ih_n[(0 * HID + d) * NIN];
            const float* wg = &W_ih_n[(2 * HID + d) * NIN];
            const float* wo = &W_ih_n[(3 * HID + d) * NIN];
#pragma unroll
            for (int j = 0; j < 10; ++j) {
                row[j]      = pack_f16(L2E  * wi[2 * j], L2E  * wi[2 * j + 1]);
                row[11 + j] = pack_f16(L2E2 * wg[2 * j], L2E2 * wg[2 * j + 1]);
                row[22 + j] = pack_f16(L2E  * wo[2 * j], L2E  * wo[2 * j + 1]);
            }
            row[10] = pack_f16(L2E  * wi[20], 0.0f);
            row[21] = pack_f16(L2E2 * wg[20], 0.0f);
            row[32] = pack_f16(L2E  * wo[20], 0.0f);
            row[57] = __float_as_uint(L2E  * (b_ih_n[0 * HID + d] + b_hh_n[0 * HID + d]));
            row[58] = __float_as_uint(L2E2 * (b_ih_n[2 * HID + d] + b_hh_n[2 * HID + d]));
            row[59] = __float_as_uint(L2E  * (b_ih_n[3 * HID + d] + b_hh_n[3 * HID + d]));
        } else {
            const int d = t - HID;
            unsigned* row = &ldsu[d * WSTRIDE];
#pragma unroll
            for (int k = 0; k < NIN; ++k) {
                row[33 + k] = pack_f16(L2E * W_nmpn[k * 2 * HID + d],
                                       L2E * W_nmpn[k * 2 * HID + HID + d]);
            }
            row[54] = pack_f16(L2E  * W_ih_e[(0 * HID + d) * EIN + 0],
                               L2E  * W_ih_e[(0 * HID + d) * EIN + 1]);
            row[55] = pack_f16(L2E2 * W_ih_e[(2 * HID + d) * EIN + 0],
                               L2E2 * W_ih_e[(2 * HID + d) * EIN + 1]);
            row[56] = pack_f16(L2E  * W_ih_e[(3 * HID + d) * EIN + 0],
                               L2E  * W_ih_e[(3 * HID + d) * EIN + 1]);
            row[60] = __float_as_uint(L2E  * (b_ih_e[0 * HID + d] + b_hh_e[0 * HID + d]));
            row[61] = __float_as_uint(L2E2 * (b_ih_e[2 * HID + d] + b_hh_e[2 * HID + d]));
            row[62] = __float_as_uint(L2E  * (b_ih_e[3 * HID + d] + b_hh_e[3 * HID + d]));
#pragma unroll
            for (int c = 0; c < NCLS; ++c) row[63 + c] = __float_as_uint(W_fc[c * HID + d]);
        }
    }
    __syncthreads();

    // ---------------- per-node inputs: 2 nodes per thread ----------------
    const int base = blockIdx.x * 256;
    const int n0 = base + tid;
    const int n1 = base + tid + 128;
    const int i0 = (n0 < N) ? n0 : (N - 1);
    const int i1 = (n1 < N) ? n1 : (N - 1);

    unsigned x0[11], x1[11];
#pragma unroll
    for (int j = 0; j < 10; ++j) {
        x0[j] = pack_f16(node_feat[i0 * NIN + 2 * j], node_feat[i0 * NIN + 2 * j + 1]);
        x1[j] = pack_f16(node_feat[i1 * NIN + 2 * j], node_feat[i1 * NIN + 2 * j + 1]);
    }
    x0[10] = pack_f16(node_feat[i0 * NIN + 20], 0.0f);
    x1[10] = pack_f16(node_feat[i1 * NIN + 20], 0.0f);
    const unsigned xe0 = pack_f16(edge_feat[i0 * EIN + 0], edge_feat[i0 * EIN + 1]);
    const unsigned xe1 = pack_f16(edge_feat[i1 * EIN + 0], edge_feat[i1 * EIN + 1]);

    float a0[NIN], a1[NIN];
#pragma unroll
    for (int k = 0; k < NIN; ++k) { a0[k] = L2E * b_nmpn[k]; a1[k] = a0[k]; }
    float l0[NCLS], l1[NCLS];
#pragma unroll
    for (int k = 0; k < NCLS; ++k) { l0[k] = b_fc[k]; l1[k] = l0[k]; }

    // ================= iteration 1 =================
#pragma unroll 2
    for (int d = 0; d < HID; ++d) {
        const unsigned* row = &ldsu[d * WSTRIDE];

        float gi0 = __uint_as_float(row[57]), gi1 = gi0;
        float gg0 = __uint_as_float(row[58]), gg1 = gg0;
        float go0 = __uint_as_float(row[59]), go1 = go0;
#pragma unroll
        for (int j = 0; j < 11; ++j) {
            const unsigned wi = row[j], wg = row[11 + j], wo = row[22 + j];
            gi0 = fdot2_(x0[j], wi, gi0);  gi1 = fdot2_(x1[j], wi, gi1);
            gg0 = fdot2_(x0[j], wg, gg0);  gg1 = fdot2_(x1[j], wg, gg1);
            go0 = fdot2_(x0[j], wo, go0);  go1 = fdot2_(x1[j], wo, go1);
        }
        const float cn0 = sigmoid_pre(gi0) * tanh_pre(gg0);
        const float hn0 = sigmoid_pre(go0) * tanh_(cn0);
        const float cn1 = sigmoid_pre(gi1) * tanh_pre(gg1);
        const float hn1 = sigmoid_pre(go1) * tanh_(cn1);

        const unsigned w54 = row[54], w55 = row[55], w56 = row[56];
        const float b60 = __uint_as_float(row[60]);
        const float b61 = __uint_as_float(row[61]);
        const float b62 = __uint_as_float(row[62]);
        const float ei0 = fdot2_(xe0, w54, b60), ei1 = fdot2_(xe1, w54, b60);
        const float eg0 = fdot2_(xe0, w55, b61), eg1 = fdot2_(xe1, w55, b61);
        const float eo0 = fdot2_(xe0, w56, b62), eo1 = fdot2_(xe1, w56, b62);
        const float ce0 = sigmoid_pre(ei0) * tanh_pre(eg0);
        const float he0 = sigmoid_pre(eo0) * tanh_(ce0);
        const float ce1 = sigmoid_pre(ei1) * tanh_pre(eg1);
        const float he1 = sigmoid_pre(eo1) * tanh_(ce1);

        const unsigned hp0 = pack_f16(he0, hn0);
        const unsigned hp1 = pack_f16(he1, hn1);
#pragma unroll
        for (int k = 0; k < NIN; ++k) {
            const unsigned wm = row[33 + k];
            a0[k] = fdot2_(hp0, wm, a0[k]);
            a1[k] = fdot2_(hp1, wm, a1[k]);
        }
    }

    // xn1 = sigmoid(pre) -> repack as f16 pairs
#pragma unroll
    for (int j = 0; j < 10; ++j) {
        x0[j] = pack_f16(sigmoid_pre(a0[2 * j]), sigmoid_pre(a0[2 * j + 1]));
        x1[j] = pack_f16(sigmoid_pre(a1[2 * j]), sigmoid_pre(a1[2 * j + 1]));
    }
    x0[10] = pack_f16(sigmoid_pre(a0[20]), 0.0f);
    x1[10] = pack_f16(sigmoid_pre(a1[20]), 0.0f);

    // ================= iteration 2 (only h_n matters) =================
#pragma unroll 2
    for (int d = 0; d < HID; ++d) {
        const unsigned* row = &ldsu[d * WSTRIDE];

        float gi0 = __uint_as_float(row[57]), gi1 = gi0;
        float gg0 = __uint_as_float(row[58]), gg1 = gg0;
        float go0 = __uint_as_float(row[59]), go1 = go0;
#pragma unroll
        for (int j = 0; j < 11; ++j) {
            const unsigned wi = row[j], wg = row[11 + j], wo = row[22 + j];
            gi0 = fdot2_(x0[j], wi, gi0);  gi1 = fdot2_(x1[j], wi, gi1);
            gg0 = fdot2_(x0[j], wg, gg0);  gg1 = fdot2_(x1[j], wg, gg1);
            go0 = fdot2_(x0[j], wo, go0);  go1 = fdot2_(x1[j], wo, go1);
        }
        const float cn0 = sigmoid_pre(gi0) * tanh_pre(gg0);
        const float hn0 = sigmoid_pre(go0) * tanh_(cn0);
        const float cn1 = sigmoid_pre(gi1) * tanh_pre(gg1);
        const float hn1 = sigmoid_pre(go1) * tanh_(cn1);

        const float f0 = __uint_as_float(row[63]);
        const float f1 = __uint_as_float(row[64]);
        const float f2 = __uint_as_float(row[65]);
        const float f3 = __uint_as_float(row[66]);
        l0[0] = fmaf(hn0, f0, l0[0]);  l1[0] = fmaf(hn1, f0, l1[0]);
        l0[1] = fmaf(hn0, f1, l0[1]);  l1[1] = fmaf(hn1, f1, l1[1]);
        l0[2] = fmaf(hn0, f2, l0[2]);  l1[2] = fmaf(hn1, f2, l1[2]);
        l0[3] = fmaf(hn0, f3, l0[3]);  l1[3] = fmaf(hn1, f3, l1[3]);
    }

    // ================= log_softmax over 4 classes + store =================
    {
        const float m = fmaxf(fmaxf(l0[0], l0[1]), fmaxf(l0[2], l0[3]));
        float s = 0.0f;
#pragma unroll
        for (int k = 0; k < NCLS; ++k) s += exp2_(L2E * (l0[k] - m));
        const float lse = __logf(s) + m;
        if (n0 < N) {
            float4 o4;
            o4.x = l0[0] - lse; o4.y = l0[1] - lse;
            o4.z = l0[2] - lse; o4.w = l0[3] - lse;
            *reinterpret_cast<float4*>(&out[n0 * NCLS]) = o4;
        }
    }
    {
        const float m = fmaxf(fmaxf(l1[0], l1[1]), fmaxf(l1[2], l1[3]));
        float s = 0.0f;
#pragma unroll
        for (int k = 0; k < NCLS; ++k) s += exp2_(L2E * (l1[k] - m));
        const float lse = __logf(s) + m;
        if (n1 < N) {
            float4 o4;
            o4.x = l1[0] - lse; o4.y = l1[1] - lse;
            o4.z = l1[2] - lse; o4.w = l1[3] - lse;
            *reinterpret_cast<float4*>(&out[n1 * NCLS]) = o4;
        }
    }
}

extern "C" void kernel_launch(void* const* d_in, const int* in_sizes, int n_in,
                              void* d_out, int out_size, void* d_ws, size_t ws_size,
                              hipStream_t stream)
{
    // setup_inputs order:
    // 0 node_feat, 1 edge_feat, 2 src, 3 dst, 4 W_ih_n, 5 W_hh_n, 6 b_ih_n,
    // 7 b_hh_n, 8 W_ih_e, 9 W_hh_e, 10 b_ih_e, 11 b_hh_e, 12 W_nmpn,
    // 13 b_nmpn, 14 W_empn, 15 b_empn, 16 W_fc, 17 b_fc
    const float* node_feat = (const float*)d_in[0];
    const float* edge_feat = (const float*)d_in[1];
    const float* W_ih_n    = (const float*)d_in[4];
    const float* b_ih_n    = (const float*)d_in[6];
    const float* b_hh_n    = (const float*)d_in[7];
    const float* W_ih_e    = (const float*)d_in[8];
    const float* b_ih_e    = (const float*)d_in[10];
    const float* b_hh_e    = (const float*)d_in[11];
    const float* W_nmpn    = (const float*)d_in[12];
    const float* b_nmpn    = (const float*)d_in[13];
    const float* W_fc      = (const float*)d_in[16];
    const float* b_fc      = (const float*)d_in[17];
    float* out = (float*)d_out;

    const int N = in_sizes[0] / NIN;

    const int block = 128;                      // 2 waves/block, 2 nodes/thread
    const int grid = (N + 256 - 1) / 256;       // 782 blocks of 256 nodes
    fused_gnn_kernel<<<grid, block, 0, stream>>>(
        node_feat, edge_feat,
        W_ih_n, b_ih_n, b_hh_n,
        W_ih_e, b_ih_e, b_hh_e,
        W_nmpn, b_nmpn, W_fc, b_fc,
        out, N);
}